// Round 4
// baseline (241.770 us; speedup 1.0000x reference)
//
#include <hip/hip_runtime.h>
#include <hip/hip_bf16.h>

#define LLEN 384
#define CDIM 256
#define NH 8
#define HD 32
#define DIN 128
#define LN_EPS 1e-5f
#define SCL 0.17677669529663687f   // 1/sqrt(32)

typedef __attribute__((ext_vector_type(8))) short bh8;
typedef __attribute__((ext_vector_type(4))) float f32x4;
typedef __attribute__((ext_vector_type(4))) unsigned int u32x4;

__device__ __forceinline__ unsigned short f2bf(float f){
  unsigned int u = __float_as_uint(f);
  u += 0x7fffu + ((u >> 16) & 1u);
  return (unsigned short)(u >> 16);
}

// Pack two fp32 -> one dword of 2 bf16 (RNE). HW v_cvt_pk_bf16_f32 on gfx950.
__device__ __forceinline__ unsigned int pkbf(float a, float b){
#if defined(__gfx950__) && __has_builtin(__builtin_amdgcn_cvt_pk_bf16_f32)
  typedef __attribute__((ext_vector_type(2))) __bf16 vbf2;
  vbf2 v = __builtin_amdgcn_cvt_pk_bf16_f32(a, b);
  union { vbf2 v; unsigned int u; } cv; cv.v = v; return cv.u;
#else
  return (unsigned int)f2bf(a) | ((unsigned int)f2bf(b) << 16);
#endif
}

// ---------------------------------------------------------------------------
// Pack weights (fp32 row-major [K][N]) into bf16 MFMA fragment order.
// The same packed form serves as B-frag (k on quad dim, n on lane&15) and as
// A-frag for the operand-swapped GEMMs (k on quad dim, m on lane&15).
// ---------------------------------------------------------------------------
__global__ __launch_bounds__(256) void pack_w(
    const float* __restrict__ Wpre, const float* __restrict__ Weq,
    const float* __restrict__ Wek,  const float* __restrict__ Wq,
    const float* __restrict__ Wk,   const float* __restrict__ Wv,
    unsigned short* __restrict__ Pp, unsigned short* __restrict__ Pq,
    unsigned short* __restrict__ Pk, unsigned short* __restrict__ PWq,
    unsigned short* __restrict__ PWk, unsigned short* __restrict__ PWv)
{
  int tid = blockIdx.x * 256 + threadIdx.x;   // 176 blocks * 256 = 45056
  const float* W; unsigned short* P; int base;
  if      (tid <  4096){ W = Wpre; P = Pp;  base = tid;         }
  else if (tid < 12288){ W = Weq;  P = Pq;  base = tid -  4096; }
  else if (tid < 20480){ W = Wek;  P = Pk;  base = tid - 12288; }
  else if (tid < 28672){ W = Wq;   P = PWq; base = tid - 20480; }
  else if (tid < 36864){ W = Wk;   P = PWk; base = tid - 28672; }
  else                 { W = Wv;   P = PWv; base = tid - 36864; }
  int l   = base & 63;
  int c   = (base >> 6) & 15;
  int kc  = base >> 10;
  int krow = kc*32 + (l >> 4)*8;
  int col  = c*16 + (l & 15);
  unsigned int wds[4];
  #pragma unroll
  for (int p = 0; p < 4; p++){
    unsigned short lo = f2bf(W[(size_t)(krow + 2*p    )*CDIM + col]);
    unsigned short hi = f2bf(W[(size_t)(krow + 2*p + 1)*CDIM + col]);
    wds[p] = (unsigned int)lo | ((unsigned int)hi << 16);
  }
  uint4 v; v.x = wds[0]; v.y = wds[1]; v.z = wds[2]; v.w = wds[3];
  *(uint4*)(P + (size_t)base*8) = v;
}

// ---------------------------------------------------------------------------
// qkv: 18 blocks (jb 0..5 x m 0..2).
//  m=0: Qm (fp32 row-major) + QmH (bf16 row-major)
//  m=1: PKt (K^T in MFMA B-frag layout, per head)
//  m=2: Vm (fp32 row-major)
// ---------------------------------------------------------------------------
__global__ __launch_bounds__(256) void qkv_mfma(
    const float* __restrict__ x3d,
    const float* __restrict__ bq, const float* __restrict__ bk, const float* __restrict__ bv,
    const unsigned short* __restrict__ PWq, const unsigned short* __restrict__ PWk,
    const unsigned short* __restrict__ PWv,
    float* __restrict__ Vm, unsigned short* __restrict__ QmH,
    float* __restrict__ Qm, unsigned short* __restrict__ PKt)
{
  __shared__ __align__(16) unsigned short Xb[64*264];
  const int bx = blockIdx.x;
  const int jb = bx / 3, m = bx % 3;
  const int t  = threadIdx.x;
  const int w  = t >> 6, l = t & 63, q4 = l >> 4, lm = l & 15;
  const int wbase = w << 6;

  const float* src = x3d + (size_t)jb*64*CDIM;
  #pragma unroll
  for (int it = 0; it < 16; it++){
    int idx = it*256 + t;             // float4 index over 64x64
    int r = idx >> 6, k4 = (idx & 63) << 2;
    f32x4 v = *(const f32x4*)(src + (size_t)r*CDIM + k4);
    unsigned int p0 = pkbf(v[0], v[1]), p1 = pkbf(v[2], v[3]);
    uint2 pk; pk.x = p0; pk.y = p1;
    *(uint2*)(&Xb[r*264 + k4]) = pk;
  }
  __syncthreads();

  const unsigned short* P = (m == 0) ? PWq : (m == 1) ? PWk : PWv;
  const float* bias       = (m == 0) ? bq  : (m == 1) ? bk  : bv;
  f32x4 acc[4][4];
  #pragma unroll
  for (int a = 0; a < 4; a++)
    #pragma unroll
    for (int b = 0; b < 4; b++){ f32x4 z = {0.f,0.f,0.f,0.f}; acc[a][b] = z; }
  #pragma unroll
  for (int kc = 0; kc < 8; kc++){
    bh8 af[4];
    #pragma unroll
    for (int rt = 0; rt < 4; rt++)
      af[rt] = *(const bh8*)(&Xb[(rt*16 + lm)*264 + kc*32 + q4*8]);
    #pragma unroll
    for (int ct = 0; ct < 4; ct++){
      bh8 bf = *(const bh8*)(P + ((size_t)(kc*16 + (w*4 + ct))*64 + l)*8);
      #pragma unroll
      for (int rt = 0; rt < 4; rt++)
        acc[rt][ct] = __builtin_amdgcn_mfma_f32_16x16x32_bf16(af[rt], bf, acc[rt][ct], 0, 0, 0);
    }
  }
  #pragma unroll
  for (int ct = 0; ct < 4; ct++){
    int c = wbase + ct*16 + lm;
    float bb = bias[c];
    #pragma unroll
    for (int rt = 0; rt < 4; rt++)
      #pragma unroll
      for (int rg = 0; rg < 4; rg++){
        int row = jb*64 + rt*16 + q4*4 + rg;
        float v = acc[rt][ct][rg] + bb;
        if (m == 0){
          Qm[(size_t)row*CDIM + c] = v;
          QmH[(size_t)row*CDIM + c] = f2bf(v);
        } else if (m == 1){
          int kc2 = c >> 5;            // head
          int jj2 = c & 7;
          int l2  = ((c >> 3) & 3)*16 + (row & 15);
          PKt[(((size_t)kc2*24 + (row >> 4))*64 + l2)*8 + jj2] = f2bf(v);
        } else {
          Vm[(size_t)row*CDIM + c] = v;
        }
      }
  }
}

// ---------------------------------------------------------------------------
// Main tile kernel: one block per (i, j-tile). 2304 blocks, 4 blocks/CU.
// GEMM1/GEMM2 are operand-swapped (D = W^T X^T: c on reg dim, j on lane dim)
// so LN stats / E-write / score reductions are cheap. GEMM3 unswapped.
// ---------------------------------------------------------------------------
__global__ __launch_bounds__(256, 4) void x3d_tiles(
  const float* __restrict__ x2d,
  const float* __restrict__ bpre, const float* __restrict__ ln_g, const float* __restrict__ ln_b,
  const float* __restrict__ beq,  const float* __restrict__ bek,
  const float* __restrict__ Qm,   const unsigned short* __restrict__ QmH,
  const unsigned short* __restrict__ PKt,
  const unsigned short* __restrict__ Pp, const unsigned short* __restrict__ Pq,
  const unsigned short* __restrict__ Pk,
  float* __restrict__ Sg, float* __restrict__ x2part)
{
  __shared__ __align__(16) unsigned short EX[64*264];      // 33792 B
  __shared__ float rowstat[4][64][2];                      //  2048 B
  __shared__ float muS[64], istdS[64];                     //   512 B
  __shared__ __align__(16) float scoresS[NH*64];           //  2048 B (qk1, then scores)
  // total LDS 38400 B -> 4 blocks/CU

  const int bx = blockIdx.x;
  const int i = bx / 6, jt = bx % 6, j0 = jt * 64;
  const int t = threadIdx.x;
  const int w = t >> 6, l = t & 63, q4 = l >> 4, lm = l & 15;
  const int wbase = w << 6;
  const bool b4 = l & 16, b5 = l & 32;

  // ---- term1 via MFMA: scoresS[h][j] = q_i(h).k_j(h); wave w does h=2w,2w+1
  #pragma unroll
  for (int hh = 0; hh < 2; hh++){
    int h = 2*w + hh;
    bh8 aq = *(const bh8*)(QmH + (size_t)i*CDIM + h*HD + q4*8);
    #pragma unroll
    for (int ct = 0; ct < 4; ct++){
      bh8 bf = *(const bh8*)(PKt + (((size_t)h*24 + (jt*4 + ct))*64 + l)*8);
      f32x4 z = {0.f,0.f,0.f,0.f};
      f32x4 a1 = __builtin_amdgcn_mfma_f32_16x16x32_bf16(aq, bf, z, 0, 0, 0);
      if (q4 == 0) scoresS[h*64 + ct*16 + lm] = a1[0];
    }
  }

  // ---- stage x2d tile (64 x 128) as bf16, stride 136 (non-temporal) ----
  {
    const float* src = x2d + ((size_t)i*LLEN + j0)*DIN;
    #pragma unroll
    for (int it = 0; it < 8; it++){
      int r  = it*8 + (t >> 5);
      int k4 = (t & 31)*4;
      u32x4 uv = __builtin_nontemporal_load((const u32x4*)(src + (size_t)r*DIN + k4));
      uint2 pk;
      pk.x = pkbf(__uint_as_float(uv.x), __uint_as_float(uv.y));
      pk.y = pkbf(__uint_as_float(uv.z), __uint_as_float(uv.w));
      *(uint2*)(&EX[r*136 + k4]) = pk;
    }
  }
  __syncthreads();

  // ---- GEMM1 (swapped): acc[mt][nt] = Epre^T, c = wbase+mt*16+q4*4+reg, j = nt*16+lm
  f32x4 acc[4][4];
  #pragma unroll
  for (int a = 0; a < 4; a++)
    #pragma unroll
    for (int b = 0; b < 4; b++){ f32x4 z = {0.f,0.f,0.f,0.f}; acc[a][b] = z; }
  #pragma unroll
  for (int kc = 0; kc < 4; kc++){
    bh8 xf[4];
    #pragma unroll
    for (int nt = 0; nt < 4; nt++)
      xf[nt] = *(const bh8*)(&EX[(nt*16 + lm)*136 + kc*32 + q4*8]);
    #pragma unroll
    for (int mt = 0; mt < 4; mt++){
      bh8 wf = *(const bh8*)(Pp + ((size_t)(kc*16 + (w*4 + mt))*64 + l)*8);
      #pragma unroll
      for (int nt = 0; nt < 4; nt++)
        acc[mt][nt] = __builtin_amdgcn_mfma_f32_16x16x32_bf16(wf, xf[nt], acc[mt][nt], 0, 0, 0);
    }
  }

  // ---- + bpre, LN stats per j (local over c + 6 packed shuffles) ----
  {
    float vs[4] = {0,0,0,0}, vq[4] = {0,0,0,0};
    #pragma unroll
    for (int mt = 0; mt < 4; mt++){
      int cb = wbase + mt*16 + q4*4;
      f32x4 bp = *(const f32x4*)(bpre + cb);
      #pragma unroll
      for (int nt = 0; nt < 4; nt++)
        #pragma unroll
        for (int rg = 0; rg < 4; rg++){
          float x = acc[mt][nt][rg] + bp[rg];
          acc[mt][nt][rg] = x;
          vs[nt] += x; vq[nt] += x*x;
        }
    }
    float r0 = (b4 ? vs[1] : vs[0]) + __shfl_xor(b4 ? vs[0] : vs[1], 16, 64);
    float r1 = (b4 ? vs[3] : vs[2]) + __shfl_xor(b4 ? vs[2] : vs[3], 16, 64);
    float ssum = (b5 ? r1 : r0) + __shfl_xor(b5 ? r0 : r1, 32, 64);
    float u0 = (b4 ? vq[1] : vq[0]) + __shfl_xor(b4 ? vq[0] : vq[1], 16, 64);
    float u1 = (b4 ? vq[3] : vq[2]) + __shfl_xor(b4 ? vq[2] : vq[3], 16, 64);
    float ssq = (b5 ? u1 : u0) + __shfl_xor(b5 ? u0 : u1, 32, 64);
    int ntl = (b5 ? 2 : 0) + (b4 ? 1 : 0);
    int jl = ntl*16 + lm;
    rowstat[w][jl][0] = ssum;
    rowstat[w][jl][1] = ssq;
  }
  __syncthreads();
  if (t < 64){
    float s  = rowstat[0][t][0] + rowstat[1][t][0] + rowstat[2][t][0] + rowstat[3][t][0];
    float s2 = rowstat[0][t][1] + rowstat[1][t][1] + rowstat[2][t][1] + rowstat[3][t][1];
    float mu = s * (1.f/256.f);
    float var = s2 * (1.f/256.f) - mu*mu;
    muS[t] = mu;
    istdS[t] = rsqrtf(var + LN_EPS);
  }
  __syncthreads();

  // ---- LN + ReLU -> bf16 E tile (stride 264), b64 writes ----
  {
    float muL[4], isL[4];
    #pragma unroll
    for (int nt = 0; nt < 4; nt++){
      muL[nt] = muS[nt*16 + lm];
      isL[nt] = istdS[nt*16 + lm];
    }
    #pragma unroll
    for (int mt = 0; mt < 4; mt++){
      int cb = wbase + mt*16 + q4*4;
      f32x4 g4 = *(const f32x4*)(ln_g + cb);
      f32x4 bb4 = *(const f32x4*)(ln_b + cb);
      #pragma unroll
      for (int nt = 0; nt < 4; nt++){
        float e0 = fmaxf((acc[mt][nt][0] - muL[nt])*isL[nt]*g4[0] + bb4[0], 0.f);
        float e1 = fmaxf((acc[mt][nt][1] - muL[nt])*isL[nt]*g4[1] + bb4[1], 0.f);
        float e2 = fmaxf((acc[mt][nt][2] - muL[nt])*isL[nt]*g4[2] + bb4[2], 0.f);
        float e3 = fmaxf((acc[mt][nt][3] - muL[nt])*isL[nt]*g4[3] + bb4[3], 0.f);
        uint2 pk; pk.x = pkbf(e0, e1); pk.y = pkbf(e2, e3);
        *(uint2*)(&EX[(nt*16 + lm)*264 + cb]) = pk;
      }
    }
  }
  __syncthreads();

  // ---- GEMM2 (swapped): acc = EFK^T ----
  #pragma unroll
  for (int a = 0; a < 4; a++)
    #pragma unroll
    for (int b = 0; b < 4; b++){ f32x4 z = {0.f,0.f,0.f,0.f}; acc[a][b] = z; }
  #pragma unroll
  for (int kc = 0; kc < 8; kc++){
    bh8 xf[4];
    #pragma unroll
    for (int nt = 0; nt < 4; nt++)
      xf[nt] = *(const bh8*)(&EX[(nt*16 + lm)*264 + kc*32 + q4*8]);
    #pragma unroll
    for (int mt = 0; mt < 4; mt++){
      bh8 wf = *(const bh8*)(Pk + ((size_t)(kc*16 + (w*4 + mt))*64 + l)*8);
      #pragma unroll
      for (int nt = 0; nt < 4; nt++)
        acc[mt][nt] = __builtin_amdgcn_mfma_f32_16x16x32_bf16(wf, xf[nt], acc[mt][nt], 0, 0, 0);
    }
  }

  // ---- scores: per-j head reduction (2 shuffles each) + qk1 + scale ----
  {
    f32x4 bk4[4];
    #pragma unroll
    for (int mt = 0; mt < 4; mt++)
      bk4[mt] = *(const f32x4*)(bek + wbase + mt*16 + q4*4);
    #pragma unroll
    for (int nt = 0; nt < 4; nt++){
      int j = nt*16 + lm;
      float v0 = 0.f, v1 = 0.f;
      #pragma unroll
      for (int mt = 0; mt < 4; mt++){
        int cb = wbase + mt*16 + q4*4;
        f32x4 qv = *(const f32x4*)(Qm + (size_t)(j0 + j)*CDIM + cb);
        float p = (acc[mt][nt][0] + bk4[mt][0]) * qv[0]
                + (acc[mt][nt][1] + bk4[mt][1]) * qv[1]
                + (acc[mt][nt][2] + bk4[mt][2]) * qv[2]
                + (acc[mt][nt][3] + bk4[mt][3]) * qv[3];
        if (mt < 2) v0 += p; else v1 += p;
      }
      float r = (b4 ? v1 : v0) + __shfl_xor(b4 ? v0 : v1, 16, 64);
      float s = r + __shfl_xor(r, 32, 64);
      int h = 2*w + (b4 ? 1 : 0);
      float sc = (s + scoresS[h*64 + j]) * SCL;
      if (!b5){
        scoresS[h*64 + j] = sc;
        Sg[((size_t)i*NH + h)*LLEN + j0 + j] = sc;
      }
    }
  }
  // scoresS write->read below is wave-local (wave w only touches h=2w,2w+1)

  // ---- GEMM3 (unswapped): acc = EFQ, j on rows, c on lanes ----
  #pragma unroll
  for (int a = 0; a < 4; a++)
    #pragma unroll
    for (int b = 0; b < 4; b++){ f32x4 z = {0.f,0.f,0.f,0.f}; acc[a][b] = z; }
  #pragma unroll
  for (int kc = 0; kc < 8; kc++){
    bh8 af[4];
    #pragma unroll
    for (int rt = 0; rt < 4; rt++)
      af[rt] = *(const bh8*)(&EX[(rt*16 + lm)*264 + kc*32 + q4*8]);
    #pragma unroll
    for (int ct = 0; ct < 4; ct++){
      bh8 bf = *(const bh8*)(Pq + ((size_t)(kc*16 + (w*4 + ct))*64 + l)*8);
      #pragma unroll
      for (int rt = 0; rt < 4; rt++)
        acc[rt][ct] = __builtin_amdgcn_mfma_f32_16x16x32_bf16(af[rt], bf, acc[rt][ct], 0, 0, 0);
    }
  }

  // ---- x2 partials: x2[c] += s[h(c)][j]*(efq[j,c]+beq[c]) ----
  {
    float bq4[4];
    #pragma unroll
    for (int ct = 0; ct < 4; ct++) bq4[ct] = beq[wbase + ct*16 + lm];
    float x2p[4] = {0.f, 0.f, 0.f, 0.f};
    #pragma unroll
    for (int rt = 0; rt < 4; rt++){
      f32x4 s0 = *(const f32x4*)(&scoresS[(2*w    )*64 + rt*16 + q4*4]);
      f32x4 s1 = *(const f32x4*)(&scoresS[(2*w + 1)*64 + rt*16 + q4*4]);
      #pragma unroll
      for (int ct = 0; ct < 4; ct++){
        const f32x4& sv = (ct < 2) ? s0 : s1;
        #pragma unroll
        for (int rg = 0; rg < 4; rg++)
          x2p[ct] = fmaf(sv[rg], acc[rt][ct][rg] + bq4[ct], x2p[ct]);
      }
    }
    float r0 = (b4 ? x2p[1] : x2p[0]) + __shfl_xor(b4 ? x2p[0] : x2p[1], 16, 64);
    float r1 = (b4 ? x2p[3] : x2p[2]) + __shfl_xor(b4 ? x2p[2] : x2p[3], 16, 64);
    float q  = (b5 ? r1 : r0) + __shfl_xor(b5 ? r0 : r1, 32, 64);
    int ctq = (b4 ? 1 : 0) | (b5 ? 2 : 0);
    x2part[((size_t)jt*LLEN + i)*CDIM + wbase + ctq*16 + lm] = q;
  }
}

// ---------------------------------------------------------------------------
// finish: softmax + x1 + x2 + out-proj. 384 blocks.
// ---------------------------------------------------------------------------
__global__ __launch_bounds__(256) void finish(
    const float* __restrict__ Sg, const float* __restrict__ x2part,
    const float* __restrict__ Vm, const float* __restrict__ Wo,
    const float* __restrict__ bo, float* __restrict__ out)
{
  __shared__ float scoresS[NH*LLEN];   // 12 KB
  __shared__ float xoutS[CDIM];
  const int i = blockIdx.x;
  const int t = threadIdx.x;

  #pragma unroll
  for (int it = 0; it < 3; it++)
    ((float4*)scoresS)[it*256 + t] = ((const float4*)(Sg + (size_t)i*NH*LLEN))[it*256 + t];
  __syncthreads();

  const int h = t >> 5;
  const int g32 = t & 31;
  float sv[12];
  float mx = -3.0e38f;
  #pragma unroll
  for (int it = 0; it < 12; it++){
    float s = scoresS[h*LLEN + it*32 + g32];
    sv[it] = s;
    mx = fmaxf(mx, s);
  }
  #pragma unroll
  for (int mk = 1; mk < 32; mk <<= 1) mx = fmaxf(mx, __shfl_xor(mx, mk, 64));
  float den = 0.f;
  #pragma unroll
  for (int it = 0; it < 12; it++){ float e = __expf(sv[it] - mx); sv[it] = e; den += e; }
  #pragma unroll
  for (int mk = 1; mk < 32; mk <<= 1) den += __shfl_xor(den, mk, 64);
  float rden = 1.f / den;
  #pragma unroll
  for (int it = 0; it < 12; it++) scoresS[h*LLEN + it*32 + g32] = sv[it]*rden;
  __syncthreads();

  float a0 = 0.f, a1 = 0.f, a2 = 0.f, a3 = 0.f;
  {
    const float* vp = Vm + t;
    const float* sp = scoresS + h*LLEN;
    #pragma unroll 4
    for (int j = 0; j < LLEN; j += 4){
      a0 = fmaf(sp[j+0], vp[(size_t)(j+0)*CDIM], a0);
      a1 = fmaf(sp[j+1], vp[(size_t)(j+1)*CDIM], a1);
      a2 = fmaf(sp[j+2], vp[(size_t)(j+2)*CDIM], a2);
      a3 = fmaf(sp[j+3], vp[(size_t)(j+3)*CDIM], a3);
    }
  }
  float x2v = 0.f;
  #pragma unroll
  for (int jt = 0; jt < 6; jt++)
    x2v += x2part[((size_t)jt*LLEN + i)*CDIM + t];
  xoutS[t] = (a0 + a1) + (a2 + a3) + x2v;
  __syncthreads();

  float b0a = bo[t], b1a = 0.f, b2a = 0.f, b3a = 0.f;
  #pragma unroll 4
  for (int c = 0; c < CDIM; c += 4){
    b0a = fmaf(xoutS[c+0], Wo[(size_t)(c+0)*CDIM + t], b0a);
    b1a = fmaf(xoutS[c+1], Wo[(size_t)(c+1)*CDIM + t], b1a);
    b2a = fmaf(xoutS[c+2], Wo[(size_t)(c+2)*CDIM + t], b2a);
    b3a = fmaf(xoutS[c+3], Wo[(size_t)(c+3)*CDIM + t], b3a);
  }
  out[(size_t)i*CDIM + t] = (b0a + b1a) + (b2a + b3a);
}

// ---------------------------------------------------------------------------
extern "C" void kernel_launch(void* const* d_in, const int* in_sizes, int n_in,
                              void* d_out, int out_size, void* d_ws, size_t ws_size,
                              hipStream_t stream)
{
  const float* x2d  = (const float*)d_in[0];
  const float* x3d  = (const float*)d_in[1];
  const float* Wq   = (const float*)d_in[2];
  const float* bq   = (const float*)d_in[3];
  const float* Wk   = (const float*)d_in[4];
  const float* bk   = (const float*)d_in[5];
  const float* Wv   = (const float*)d_in[6];
  const float* bv   = (const float*)d_in[7];
  const float* Wpre = (const float*)d_in[8];
  const float* bpre = (const float*)d_in[9];
  const float* ln_g = (const float*)d_in[10];
  const float* ln_b = (const float*)d_in[11];
  const float* Weq  = (const float*)d_in[12];
  const float* beq  = (const float*)d_in[13];
  const float* Wek  = (const float*)d_in[14];
  const float* bek  = (const float*)d_in[15];
  const float* Wo   = (const float*)d_in[16];
  const float* bo   = (const float*)d_in[17];
  float* out = (float*)d_out;

  float* Vm = (float*)d_ws;                                  // 384*256 f32
  float* Qm = Vm + LLEN*CDIM;                                // 384*256 f32
  unsigned short* QmH = (unsigned short*)(Qm + LLEN*CDIM);   // 384*256 bf16
  unsigned short* PKt = QmH + LLEN*CDIM;                     // 8*24*64*8 bf16
  unsigned short* Pp  = PKt + LLEN*CDIM;                     // 128*256
  unsigned short* Pq  = Pp  + DIN*CDIM;                      // 256*256
  unsigned short* Pk  = Pq  + CDIM*CDIM;
  unsigned short* PWq = Pk  + CDIM*CDIM;
  unsigned short* PWk = PWq + CDIM*CDIM;
  unsigned short* PWv = PWk + CDIM*CDIM;
  float* Sg     = (float*)(PWv + CDIM*CDIM);                 // 384*8*384 f32
  float* x2part = Sg + (size_t)LLEN*NH*LLEN;                 // 6*384*256 f32

  pack_w<<<dim3(176), dim3(256), 0, stream>>>(Wpre, Weq, Wek, Wq, Wk, Wv,
                                              Pp, Pq, Pk, PWq, PWk, PWv);
  qkv_mfma<<<dim3(18), dim3(256), 0, stream>>>(x3d, bq, bk, bv, PWq, PWk, PWv,
                                               Vm, QmH, Qm, PKt);
  x3d_tiles<<<dim3(LLEN*6), dim3(256), 0, stream>>>(x2d, bpre, ln_g, ln_b, beq, bek,
                                                    Qm, QmH, PKt, Pp, Pq, Pk, Sg, x2part);
  finish<<<dim3(LLEN), dim3(256), 0, stream>>>(Sg, x2part, Vm, Wo, bo, out);
}